// Round 3
// baseline (448.662 us; speedup 1.0000x reference)
//
#include <hip/hip_runtime.h>

// Aggregate = column segment-sum: out[b][g] = sum_{c: sid[c]==g} x[b][c]
// x: [8192, 8192] f32, sid: [8192] i32 in [0,512), out: [8192, 512] f32.
//
// R1: LDS atomic scatter, 341us. R2/R3: CSR gather, barrier-phased, ~170us.
// R4: single-wave blocks, cols from global scattered -> 224us (L1 txn bound).
// R5: cols in LDS + runtime-indexed double buffer rowb[2][], 178us:
//     rowb[cur] vs rowb[cur^1] NOT alias-disambiguable -> SIInsertWaitcnts
//     emits its own vmcnt(0) before the gather ds_reads, serializing every
//     row on full stage latency (HBM 10.6%, VALU 7.6%, nothing saturated).
// R6 (this): compile-time distinct buffers.
//     - bufA/bufB are SEPARATE __shared__ arrays; row loop unrolled by 2 so
//       gather target and DMA target are distinct named objects -> waitcnt
//       pass can prove no alias -> loads genuinely stay in flight across
//       the gather (8-phase-template pattern).
//     - wait-BEFORE-issue: vmcnt(2) just before staging into a buffer means
//       "the buffer I'm about to gather is complete" (2 = my two newest
//       fire-and-forget output stores). Max outstanding 34 < 63.
//     - otherwise R5 structure: 1 wave/block, no barriers, colb u16 in LDS,
//       paired u32 col reads, 80KB LDS -> 2 blocks/CU, 512 blocks x 16 rows.

#define NCLS 8192
#define NGRP 512
#define TPB  64
#define RPB  16    // rows per block

typedef float vf4 __attribute__((ext_vector_type(4)));

// d_ws layout (ints): offs[513] @0, cols16 (u16[8192] = 16KB) @1024

__global__ __launch_bounds__(512) void k_prep(const int* __restrict__ sid,
                                              int* __restrict__ offs,
                                              unsigned short* __restrict__ cols16) {
    __shared__ int hist[NGRP];
    __shared__ int tmp[NGRP];
    __shared__ int curs[NGRP];
    const int t = threadIdx.x;
    hist[t] = 0;
    __syncthreads();

    int g_[16];  // 8192 / 512 = 16 columns per thread, coalesced
#pragma unroll
    for (int i = 0; i < 16; ++i) {
        g_[i] = sid[t + 512 * i];
        atomicAdd(&hist[g_[i]], 1);
    }
    __syncthreads();

    const int h = hist[t];
    tmp[t] = h;
    __syncthreads();
    for (int off = 1; off < NGRP; off <<= 1) {
        int v = tmp[t];
        int u = (t >= off) ? tmp[t - off] : 0;
        __syncthreads();
        tmp[t] = v + u;
        __syncthreads();
    }
    const int excl = tmp[t] - h;  // exclusive prefix sum
    offs[t] = excl;
    curs[t] = excl;
    if (t == NGRP - 1) offs[NGRP] = NCLS;
    __syncthreads();

#pragma unroll
    for (int i = 0; i < 16; ++i) {
        int c = t + 512 * i;
        int pos = atomicAdd(&curs[g_[i]], 1);  // order within group irrelevant
        cols16[pos] = (unsigned short)c;
    }
}

// Stage one x-row into a compile-time-known LDS buffer: 32 x 1KB DMA.
#define STAGE(dstbuf, rowidx)                                                     \
    do {                                                                          \
        const float* xr_ = x + (size_t)(rowidx) * NCLS;                           \
        _Pragma("unroll")                                                         \
        for (int k_ = 0; k_ < 32; ++k_) {                                         \
            __builtin_amdgcn_global_load_lds(                                     \
                (const __attribute__((address_space(1))) void*)(xr_ + k_ * 256 +  \
                                                                lane * 4),        \
                (__attribute__((address_space(3))) void*)(&dstbuf[k_ * 256]),     \
                16, 0, 0);                                                        \
        }                                                                         \
    } while (0)

// Gather 8 segments from a compile-time-known buffer, store one out row.
#define GATHER_STORE(srcbuf, rowidx)                                              \
    do {                                                                          \
        float s_[8];                                                              \
        _Pragma("unroll")                                                         \
        for (int j_ = 0; j_ < 8; ++j_) {                                          \
            int p_ = o[j_];                                                       \
            const int e_ = o[j_ + 1];                                             \
            float a0 = 0.f, a1 = 0.f, a2 = 0.f, a3 = 0.f;                         \
            if ((p_ & 1) && p_ < e_) { a3 += srcbuf[colb[p_]]; ++p_; }            \
            for (; p_ + 4 <= e_; p_ += 4) {                                       \
                unsigned c0_ = *reinterpret_cast<const unsigned*>(&colb[p_]);     \
                unsigned c1_ = *reinterpret_cast<const unsigned*>(&colb[p_ + 2]); \
                a0 += srcbuf[c0_ & 0xffffu];                                      \
                a1 += srcbuf[c0_ >> 16];                                          \
                a2 += srcbuf[c1_ & 0xffffu];                                      \
                a3 += srcbuf[c1_ >> 16];                                          \
            }                                                                     \
            if (p_ + 2 <= e_) {                                                   \
                unsigned c0_ = *reinterpret_cast<const unsigned*>(&colb[p_]);     \
                a0 += srcbuf[c0_ & 0xffffu];                                      \
                a1 += srcbuf[c0_ >> 16];                                          \
                p_ += 2;                                                          \
            }                                                                     \
            if (p_ < e_) a2 += srcbuf[colb[p_]];                                  \
            s_[j_] = (a0 + a1) + (a2 + a3);                                       \
        }                                                                         \
        vf4 va_, vb_;                                                             \
        va_.x = s_[0]; va_.y = s_[1]; va_.z = s_[2]; va_.w = s_[3];               \
        vb_.x = s_[4]; vb_.y = s_[5]; vb_.z = s_[6]; vb_.w = s_[7];               \
        float* op_ = out + (size_t)(rowidx) * NGRP + g0;                          \
        __builtin_nontemporal_store(va_, reinterpret_cast<vf4*>(op_));            \
        __builtin_nontemporal_store(vb_, reinterpret_cast<vf4*>(op_ + 4));        \
    } while (0)

#define WAIT_VM2() asm volatile("s_waitcnt vmcnt(2)" ::: "memory")

__global__ __launch_bounds__(TPB) void k_main(const float* __restrict__ x,
                                              const unsigned short* __restrict__ cols16,
                                              const int* __restrict__ offs,
                                              float* __restrict__ out) {
    __shared__ float bufA[NCLS];             // 32 KB — distinct objects so the
    __shared__ float bufB[NCLS];             // 32 KB — waitcnt pass can prove
    __shared__ unsigned short colb[NCLS];    // 16 KB   DMA-vs-ds_read no-alias
    const int lane = threadIdx.x;            // 0..63, one wave per block
    const int g0 = lane * 8;                 // this lane's 8 groups
    const int row0 = blockIdx.x * RPB;

    // --- prologue ---
    // CSR ids -> LDS: 16 x 1KB DMA.
#pragma unroll
    for (int k = 0; k < 16; ++k) {
        __builtin_amdgcn_global_load_lds(
            (const __attribute__((address_space(1))) void*)(cols16 + k * 512 + lane * 8),
            (__attribute__((address_space(3))) void*)(&colb[k * 512]),
            16, 0, 0);
    }
    STAGE(bufA, row0);

    // Segment boundaries (row-invariant): 2x int4 + 1 scalar, 32B-aligned.
    int o[9];
    {
        int4 q0 = *reinterpret_cast<const int4*>(offs + g0);
        int4 q1 = *reinterpret_cast<const int4*>(offs + g0 + 4);
        o[0] = q0.x; o[1] = q0.y; o[2] = q0.z; o[3] = q0.w;
        o[4] = q1.x; o[5] = q1.y; o[6] = q1.z; o[7] = q1.w;
        o[8] = offs[g0 + 8];
    }
    asm volatile("s_waitcnt vmcnt(0)" ::: "memory");

    // --- main loop, unrolled x2: compile-time buffer alternation ---
#pragma unroll 1
    for (int rp = 0; rp < RPB / 2; ++rp) {
        const int r = row0 + 2 * rp;

        // A-half: bufA ready (waited last iter / prologue).
        STAGE(bufB, r + 1);          // outstanding: [bufB:32]
        GATHER_STORE(bufA, r);       // + [storesA:2]
        WAIT_VM2();                  // drain bufB loads; leave storesA

        // B-half: bufB ready.
        if (rp + 1 < RPB / 2) {
            STAGE(bufA, r + 2);      // outstanding: [storesA<=2][bufA:32]
        }
        GATHER_STORE(bufB, r + 1);   // + [storesB:2]
        WAIT_VM2();                  // drain storesA + bufA loads; leave storesB
    }
}

extern "C" void kernel_launch(void* const* d_in, const int* in_sizes, int n_in,
                              void* d_out, int out_size, void* d_ws, size_t ws_size,
                              hipStream_t stream) {
    const float* x   = (const float*)d_in[0];
    const int*   sid = (const int*)d_in[1];
    float*       out = (float*)d_out;

    int* ws = (int*)d_ws;
    int* offs = ws;                                         // [513]
    unsigned short* cols16 = (unsigned short*)(ws + 1024);  // 16KB

    const int nrows = in_sizes[0] / NCLS;  // 8192
    const int blocks = nrows / RPB;        // 512

    k_prep<<<1, 512, 0, stream>>>(sid, offs, cols16);
    k_main<<<blocks, TPB, 0, stream>>>(x, cols16, offs, out);
}

// Round 4
// 414.943 us; speedup vs baseline: 1.0813x; 1.0813x over previous
//
#include <hip/hip_runtime.h>

// Aggregate = column segment-sum: out[b][g] = sum_{c: sid[c]==g} x[b][c]
// x: [8192, 8192] f32, sid: [8192] i32 in [0,512), out: [8192, 512] f32.
//
// R1: LDS atomic scatter, 341us. R2/R3: CSR gather, barrier-phased, ~170us.
// R4: single-wave blocks, cols from global -> 224us (L1 txn bound).
// R5/R6: LDS cols + double-buffer variants, both 178-180us: gather is
//     LATENCY-bound (dep chain: col ds_read -> gather ds_read -> add, 4 elems
//     per ~140cyc, in-order, 2 waves/CU can't hide). Sync structure was
//     irrelevant. ALSO: single-block k_prep cost ~90us (1 CU serialized!).
// R7 (this):
//     - Row-PAIR gather: bufA+bufB staged, one col read feeds both rows
//       (half the col reads, 2x independent work per latency window).
//     - Batched cols: aligned u64 = 4 ids per ds_read_b64; branch-free
//       edge handling via weight-FMA (idx in [s,e) ? 1 : 0) — no peel chains,
//       8 independent gather chains in flight per batch.
//     - Stage next pair after gather, one vmcnt(0)/pair; exposure absorbed
//       into HBM-bound wait + covered by the other wave on the CU.
//     - Prep reverted to R0's measured ~28us multi-block chain.
//     - LDS: colb 16K + bufA 32K + bufB 32K = 80KB -> 2 blocks/CU.

#define NCLS 8192
#define NGRP 512
#define TPB  64
#define RPB  16    // rows per block -> 512 blocks

typedef float vf4 __attribute__((ext_vector_type(4)));

// d_ws (ints): hist[512] @0, offs[513] @512, curs[512] @1088, cols16 u16[8192] @1600

__global__ __launch_bounds__(512) void k_hist(const int* __restrict__ sid,
                                              int* __restrict__ hist) {
    int i = blockIdx.x * 512 + threadIdx.x;
    atomicAdd(&hist[sid[i]], 1);
}

__global__ __launch_bounds__(512) void k_scan(const int* __restrict__ hist,
                                              int* __restrict__ offs,
                                              int* __restrict__ curs) {
    __shared__ int tmp[NGRP];
    const int t = threadIdx.x;
    const int h = hist[t];
    tmp[t] = h;
    __syncthreads();
    for (int off = 1; off < NGRP; off <<= 1) {
        int v = tmp[t];
        int u = (t >= off) ? tmp[t - off] : 0;
        __syncthreads();
        tmp[t] = v + u;
        __syncthreads();
    }
    int excl = tmp[t] - h;   // exclusive prefix sum
    offs[t] = excl;
    curs[t] = excl;
    if (t == NGRP - 1) offs[NGRP] = NCLS;
}

__global__ __launch_bounds__(512) void k_scatter(const int* __restrict__ sid,
                                                 int* __restrict__ curs,
                                                 unsigned short* __restrict__ cols16) {
    int c = blockIdx.x * 512 + threadIdx.x;
    int g = sid[c];
    int pos = atomicAdd(&curs[g], 1);  // order within group irrelevant (sum)
    cols16[pos] = (unsigned short)c;
}

// Stage one x-row into a compile-time-known LDS buffer: 32 x 1KB DMA.
#define STAGE(dstbuf, rowidx)                                                     \
    do {                                                                          \
        const float* xr_ = x + (size_t)(rowidx) * NCLS;                           \
        _Pragma("unroll")                                                         \
        for (int k_ = 0; k_ < 32; ++k_) {                                         \
            __builtin_amdgcn_global_load_lds(                                     \
                (const __attribute__((address_space(1))) void*)(xr_ + k_ * 256 +  \
                                                                lane * 4),        \
                (__attribute__((address_space(3))) void*)(&dstbuf[k_ * 256]),     \
                16, 0, 0);                                                        \
        }                                                                         \
    } while (0)

// Gather BOTH rows' 8 segments; one u64 col read feeds 8 independent gathers.
// Branch-free edges: element weight = (idx in [s,e)) ? 1 : 0, folded into FMA.
#define GATHER2(bufX, bufY, rowX, rowY)                                           \
    do {                                                                          \
        float sx_[8], sy_[8];                                                     \
        _Pragma("unroll")                                                         \
        for (int j_ = 0; j_ < 8; ++j_) {                                          \
            const int s_ = o[j_], e_ = o[j_ + 1];                                 \
            float x0 = 0.f, x1 = 0.f, x2 = 0.f, x3 = 0.f;                         \
            float y0 = 0.f, y1 = 0.f, y2 = 0.f, y3 = 0.f;                         \
            for (int p_ = (s_ & ~3); p_ < e_; p_ += 4) {                          \
                unsigned long long cc_ =                                          \
                    *reinterpret_cast<const unsigned long long*>(&colb[p_]);      \
                const int c0_ = (int)(cc_ & 0xffffu);                             \
                const int c1_ = (int)((cc_ >> 16) & 0xffffu);                     \
                const int c2_ = (int)((cc_ >> 32) & 0xffffu);                     \
                const int c3_ = (int)(cc_ >> 48);                                 \
                const float w0_ = (p_ >= s_) ? 1.f : 0.f;                         \
                const float w1_ = (p_ + 1 >= s_ && p_ + 1 < e_) ? 1.f : 0.f;      \
                const float w2_ = (p_ + 2 >= s_ && p_ + 2 < e_) ? 1.f : 0.f;      \
                const float w3_ = (p_ + 3 < e_) ? 1.f : 0.f;                      \
                x0 = fmaf(w0_, bufX[c0_], x0);                                    \
                y0 = fmaf(w0_, bufY[c0_], y0);                                    \
                x1 = fmaf(w1_, bufX[c1_], x1);                                    \
                y1 = fmaf(w1_, bufY[c1_], y1);                                    \
                x2 = fmaf(w2_, bufX[c2_], x2);                                    \
                y2 = fmaf(w2_, bufY[c2_], y2);                                    \
                x3 = fmaf(w3_, bufX[c3_], x3);                                    \
                y3 = fmaf(w3_, bufY[c3_], y3);                                    \
            }                                                                     \
            sx_[j_] = (x0 + x1) + (x2 + x3);                                      \
            sy_[j_] = (y0 + y1) + (y2 + y3);                                      \
        }                                                                         \
        vf4 a_, b_;                                                               \
        a_.x = sx_[0]; a_.y = sx_[1]; a_.z = sx_[2]; a_.w = sx_[3];               \
        float* opx_ = out + (size_t)(rowX) * NGRP + g0;                           \
        __builtin_nontemporal_store(a_, reinterpret_cast<vf4*>(opx_));            \
        b_.x = sx_[4]; b_.y = sx_[5]; b_.z = sx_[6]; b_.w = sx_[7];               \
        __builtin_nontemporal_store(b_, reinterpret_cast<vf4*>(opx_ + 4));        \
        a_.x = sy_[0]; a_.y = sy_[1]; a_.z = sy_[2]; a_.w = sy_[3];               \
        float* opy_ = out + (size_t)(rowY) * NGRP + g0;                           \
        __builtin_nontemporal_store(a_, reinterpret_cast<vf4*>(opy_));            \
        b_.x = sy_[4]; b_.y = sy_[5]; b_.z = sy_[6]; b_.w = sy_[7];               \
        __builtin_nontemporal_store(b_, reinterpret_cast<vf4*>(opy_ + 4));        \
    } while (0)

__global__ __launch_bounds__(TPB) void k_main(const float* __restrict__ x,
                                              const unsigned short* __restrict__ cols16,
                                              const int* __restrict__ offs,
                                              float* __restrict__ out) {
    __shared__ unsigned short colb[NCLS];    // 16 KB: CSR column ids (u16)
    __shared__ float bufA[NCLS];             // 32 KB
    __shared__ float bufB[NCLS];             // 32 KB
    const int lane = threadIdx.x;            // 0..63, one wave per block
    const int g0 = lane * 8;                 // this lane's 8 groups
    const int row0 = blockIdx.x * RPB;

    // --- prologue: colb DMA + stage pair 0, one vmcnt(0) ---
#pragma unroll
    for (int k = 0; k < 16; ++k) {
        __builtin_amdgcn_global_load_lds(
            (const __attribute__((address_space(1))) void*)(cols16 + k * 512 + lane * 8),
            (__attribute__((address_space(3))) void*)(&colb[k * 512]),
            16, 0, 0);
    }
    STAGE(bufA, row0);
    STAGE(bufB, row0 + 1);

    // Segment boundaries (row-invariant): 2x int4 + 1 scalar, 32B-aligned.
    int o[9];
    {
        int4 q0 = *reinterpret_cast<const int4*>(offs + g0);
        int4 q1 = *reinterpret_cast<const int4*>(offs + g0 + 4);
        o[0] = q0.x; o[1] = q0.y; o[2] = q0.z; o[3] = q0.w;
        o[4] = q1.x; o[5] = q1.y; o[6] = q1.z; o[7] = q1.w;
        o[8] = offs[g0 + 8];
    }
    asm volatile("s_waitcnt vmcnt(0)" ::: "memory");

#pragma unroll 1
    for (int pr = 0; pr < RPB / 2; ++pr) {
        const int rA = row0 + 2 * pr;

        GATHER2(bufA, bufB, rA, rA + 1);

        if (pr + 1 < RPB / 2) {
            STAGE(bufA, rA + 2);
            STAGE(bufB, rA + 3);
            asm volatile("s_waitcnt vmcnt(0)" ::: "memory");
        }
    }
}

extern "C" void kernel_launch(void* const* d_in, const int* in_sizes, int n_in,
                              void* d_out, int out_size, void* d_ws, size_t ws_size,
                              hipStream_t stream) {
    const float* x   = (const float*)d_in[0];
    const int*   sid = (const int*)d_in[1];
    float*       out = (float*)d_out;

    int* ws   = (int*)d_ws;
    int* hist = ws;
    int* offs = ws + 512;
    int* curs = ws + 1088;
    unsigned short* cols16 = (unsigned short*)(ws + 1600);

    const int batch  = in_sizes[0] / NCLS;   // 8192
    const int blocks = batch / RPB;          // 512

    hipMemsetAsync(hist, 0, NGRP * sizeof(int), stream);
    k_hist<<<NCLS / 512, 512, 0, stream>>>(sid, hist);
    k_scan<<<1, NGRP, 0, stream>>>(hist, offs, curs);
    k_scatter<<<NCLS / 512, 512, 0, stream>>>(sid, curs, cols16);
    k_main<<<blocks, TPB, 0, stream>>>(x, cols16, offs, out);
}

// Round 5
// 379.527 us; speedup vs baseline: 1.1822x; 1.0933x over previous
//
#include <hip/hip_runtime.h>

// Aggregate = column segment-sum: out[b][g] = sum_{c: sid[c]==g} x[b][c]
// x: [8192, 8192] f32, sid: [8192] i32 in [0,512), out: [8192, 512] f32.
//
// R1: LDS atomic scatter, 341us. R2/R3: CSR gather, barrier-phased, ~170us.
// R4: single-wave blocks, cols from global -> 224us (L1 txn bound).
// R5/R6: LDS cols + dbuf variants, 178-180us: latency-bound gather, sync
//     structure irrelevant. R7: row-pair + batched u64 cols + weight-FMA:
//     k_main dropped below top-5 cutoff (<158us) but still 2 waves/CU
//     (Occupancy 5.5%) — ALL pipes <11% busy: exposed latency, not work.
// R8 (this): occupancy. Same 80KB LDS, but 256-thread/4-wave blocks sharing
//     the staged row: 8 waves/CU (4x R7). Thread owns 2 groups (512/256).
//     Phase per row: STAGE(next, DMA, per-wave-uniform LDS base) ->
//     GATHER(cur) -> vmcnt(0) -> one __syncthreads. Wave stalls on the
//     dependent ds_read chain now interleave 8-deep per CU.
//     Weight-FMA batched cols (u64 = 4 ids) kept from R7; float2 out store.
//     LDS: colb 16K + bufA 32K + bufB 32K = 80KB -> 2 blocks/CU.

#define NCLS 8192
#define NGRP 512
#define TPB  256
#define RPB  16    // rows per block -> 512 blocks

typedef float vf2 __attribute__((ext_vector_type(2)));

// d_ws (ints): hist[512] @0, offs[513] @512, curs[512] @1088, cols16 u16[8192] @1600

__global__ __launch_bounds__(512) void k_hist(const int* __restrict__ sid,
                                              int* __restrict__ hist) {
    int i = blockIdx.x * 512 + threadIdx.x;
    atomicAdd(&hist[sid[i]], 1);
}

__global__ __launch_bounds__(512) void k_scan(const int* __restrict__ hist,
                                              int* __restrict__ offs,
                                              int* __restrict__ curs) {
    __shared__ int tmp[NGRP];
    const int t = threadIdx.x;
    const int h = hist[t];
    tmp[t] = h;
    __syncthreads();
    for (int off = 1; off < NGRP; off <<= 1) {
        int v = tmp[t];
        int u = (t >= off) ? tmp[t - off] : 0;
        __syncthreads();
        tmp[t] = v + u;
        __syncthreads();
    }
    int excl = tmp[t] - h;   // exclusive prefix sum
    offs[t] = excl;
    curs[t] = excl;
    if (t == NGRP - 1) offs[NGRP] = NCLS;
}

__global__ __launch_bounds__(512) void k_scatter(const int* __restrict__ sid,
                                                 int* __restrict__ curs,
                                                 unsigned short* __restrict__ cols16) {
    int c = blockIdx.x * 512 + threadIdx.x;
    int g = sid[c];
    int pos = atomicAdd(&curs[g], 1);  // order within group irrelevant (sum)
    cols16[pos] = (unsigned short)c;
}

// Stage one 32KB x-row with 256 threads: 8 x 4KB DMA instrs.
// global_load_lds LDS dest is wave-uniform base + lane*16B, so each wave
// gets its own 1KB slot per instr: base = k*1024 + (tid>>6)*256 floats.
#define STAGE(dstbuf, rowidx)                                                     \
    do {                                                                          \
        const float* xr_ = x + (size_t)(rowidx) * NCLS;                           \
        _Pragma("unroll")                                                         \
        for (int k_ = 0; k_ < 8; ++k_) {                                          \
            __builtin_amdgcn_global_load_lds(                                     \
                (const __attribute__((address_space(1))) void*)(xr_ + k_ * 1024 + \
                                                                tid * 4),         \
                (__attribute__((address_space(3))) void*)(&dstbuf[k_ * 1024 +     \
                                                                  wslot]),        \
                16, 0, 0);                                                        \
        }                                                                         \
    } while (0)

// Gather this thread's 2 segments from srcbuf; one u64 col read = 4 ids;
// branch-free edges via weight-FMA. Coalesced float2 nontemporal store.
#define GATHER_STORE(srcbuf, rowidx)                                              \
    do {                                                                          \
        float sums_[2];                                                           \
        _Pragma("unroll")                                                         \
        for (int j_ = 0; j_ < 2; ++j_) {                                          \
            const int s_ = (j_ == 0) ? o0 : o1;                                   \
            const int e_ = (j_ == 0) ? o1 : o2;                                   \
            float a0 = 0.f, a1 = 0.f, a2 = 0.f, a3 = 0.f;                         \
            for (int p_ = (s_ & ~3); p_ < e_; p_ += 4) {                          \
                unsigned long long cc_ =                                          \
                    *reinterpret_cast<const unsigned long long*>(&colb[p_]);      \
                const int c0_ = (int)(cc_ & 0xffffu);                             \
                const int c1_ = (int)((cc_ >> 16) & 0xffffu);                     \
                const int c2_ = (int)((cc_ >> 32) & 0xffffu);                     \
                const int c3_ = (int)(cc_ >> 48);                                 \
                const float w0_ = (p_ >= s_) ? 1.f : 0.f;                         \
                const float w1_ = (p_ + 1 >= s_ && p_ + 1 < e_) ? 1.f : 0.f;      \
                const float w2_ = (p_ + 2 >= s_ && p_ + 2 < e_) ? 1.f : 0.f;      \
                const float w3_ = (p_ + 3 < e_) ? 1.f : 0.f;                      \
                a0 = fmaf(w0_, srcbuf[c0_], a0);                                  \
                a1 = fmaf(w1_, srcbuf[c1_], a1);                                  \
                a2 = fmaf(w2_, srcbuf[c2_], a2);                                  \
                a3 = fmaf(w3_, srcbuf[c3_], a3);                                  \
            }                                                                     \
            sums_[j_] = (a0 + a1) + (a2 + a3);                                    \
        }                                                                         \
        vf2 v_;                                                                   \
        v_.x = sums_[0];                                                          \
        v_.y = sums_[1];                                                          \
        __builtin_nontemporal_store(                                              \
            v_, reinterpret_cast<vf2*>(out + (size_t)(rowidx) * NGRP + g0));      \
    } while (0)

#define WAIT_VM0() asm volatile("s_waitcnt vmcnt(0)" ::: "memory")

__global__ __launch_bounds__(TPB) void k_main(const float* __restrict__ x,
                                              const unsigned short* __restrict__ cols16,
                                              const int* __restrict__ offs,
                                              float* __restrict__ out) {
    __shared__ unsigned short colb[NCLS];    // 16 KB: CSR column ids (u16)
    __shared__ float bufA[NCLS];             // 32 KB
    __shared__ float bufB[NCLS];             // 32 KB
    const int tid = threadIdx.x;             // 0..255, 4 waves
    const int wslot = (tid >> 6) << 8;       // per-wave 256-float LDS slot
    const int g0 = tid * 2;                  // this thread's 2 groups
    const int row0 = blockIdx.x * RPB;

    // --- prologue ---
    // colb DMA: 4 instrs x 4KB (per-wave 512-u16 slots).
#pragma unroll
    for (int k = 0; k < 4; ++k) {
        __builtin_amdgcn_global_load_lds(
            (const __attribute__((address_space(1))) void*)(cols16 + k * 2048 + tid * 8),
            (__attribute__((address_space(3))) void*)(&colb[k * 2048 + 2 * wslot]),
            16, 0, 0);
    }
    STAGE(bufA, row0);

    // Segment boundaries (row-invariant): int2 + 1 scalar.
    int o0, o1, o2;
    {
        int2 q = *reinterpret_cast<const int2*>(offs + g0);
        o0 = q.x;
        o1 = q.y;
        o2 = offs[g0 + 2];
    }
    WAIT_VM0();
    __syncthreads();

    // --- main loop: one barrier per row, x2 unroll for distinct buffers ---
#pragma unroll 1
    for (int rp = 0; rp < RPB / 2; ++rp) {
        const int r = row0 + 2 * rp;

        // A phase: bufA ready for all waves.
        STAGE(bufB, r + 1);
        GATHER_STORE(bufA, r);
        WAIT_VM0();          // my DMA portion (+2 tiny stores) landed
        __syncthreads();     // everyone's DMA landed; all reads of bufA done

        // B phase: bufB ready.
        if (rp + 1 < RPB / 2) {
            STAGE(bufA, r + 2);
        }
        GATHER_STORE(bufB, r + 1);
        WAIT_VM0();
        __syncthreads();
    }
}

extern "C" void kernel_launch(void* const* d_in, const int* in_sizes, int n_in,
                              void* d_out, int out_size, void* d_ws, size_t ws_size,
                              hipStream_t stream) {
    const float* x   = (const float*)d_in[0];
    const int*   sid = (const int*)d_in[1];
    float*       out = (float*)d_out;

    int* ws   = (int*)d_ws;
    int* hist = ws;
    int* offs = ws + 512;
    int* curs = ws + 1088;
    unsigned short* cols16 = (unsigned short*)(ws + 1600);

    const int batch  = in_sizes[0] / NCLS;   // 8192
    const int blocks = batch / RPB;          // 512

    hipMemsetAsync(hist, 0, NGRP * sizeof(int), stream);
    k_hist<<<NCLS / 512, 512, 0, stream>>>(sid, hist);
    k_scan<<<1, NGRP, 0, stream>>>(hist, offs, curs);
    k_scatter<<<NCLS / 512, 512, 0, stream>>>(sid, curs, cols16);
    k_main<<<blocks, TPB, 0, stream>>>(x, cols16, offs, out);
}

// Round 7
// 368.148 us; speedup vs baseline: 1.2187x; 1.0309x over previous
//
#include <hip/hip_runtime.h>

// Aggregate = column segment-sum: out[b][g] = sum_{c: sid[c]==g} x[b][c]
// x: [8192, 8192] f32, sid: [8192] i32 in [0,512), out: [8192, 512] f32.
//
// R1 341us atomics; R2/R3 ~170 barrier-phased gather; R4 224 global cols;
// R5/R6 178-180 (sync-structure irrelevant); R7/R8 totals 415/379.5 —
// LDS pipe co-critical with HBM: 8192 scalar ds_read per row is the cost.
// R9: pair-interleaved LDS, FAILED (absmax 42.9): (a) colb DMA instrs were
//     spaced 2048B but cover 1024B each -> odd halves of colb garbage;
//     (b) WAIT_VM(4) left the last 2 pairB DMAs un-drained (2 stores, not 4).
// R10 (this): R9 with both bugs fixed (colb spacing 512 u16; vmcnt(2)).
//   - One global_load_lds: lanes 0-31 source row r0, lanes 32-63 row r1
//     (per-lane SOURCE addressing; LDS dest linear) -> pair[j][plane][128]:
//     col c of (r0,r1) at idx=c+(c&~127), idx+128.
//   - Gather: 2 ds_read at constant 512B delta (ds_read2-mergeable) per
//     column serve TWO rows: half the gather instrs, half the col reads.
//   - 1 block/CU: pairA+pairB (128KB) + colb 16KB = 144KB LDS, 256thr/4waves,
//     32 rows/block, 256 blocks.
//   - Counted waits: stage next pair -> gather current -> vmcnt(2) (leave my
//     2 output stores) -> barrier. Wall = max(HBM 6.4k cyc, gather ~3k).
//   - Prep chain BIT-IDENTICAL to R7/R8.

#define NCLS 8192
#define NGRP 512
#define TPB  256
#define RPB  32    // rows per block -> 256 blocks, 1/CU
#define NPH  16    // pair phases per block

typedef float vf2 __attribute__((ext_vector_type(2)));

// d_ws (ints): hist[512] @0, offs[513] @512, curs[512] @1088, cols16 u16[8192] @1600

__global__ __launch_bounds__(512) void k_hist(const int* __restrict__ sid,
                                              int* __restrict__ hist) {
    int i = blockIdx.x * 512 + threadIdx.x;
    atomicAdd(&hist[sid[i]], 1);
}

__global__ __launch_bounds__(512) void k_scan(const int* __restrict__ hist,
                                              int* __restrict__ offs,
                                              int* __restrict__ curs) {
    __shared__ int tmp[NGRP];
    const int t = threadIdx.x;
    const int h = hist[t];
    tmp[t] = h;
    __syncthreads();
    for (int off = 1; off < NGRP; off <<= 1) {
        int v = tmp[t];
        int u = (t >= off) ? tmp[t - off] : 0;
        __syncthreads();
        tmp[t] = v + u;
        __syncthreads();
    }
    int excl = tmp[t] - h;   // exclusive prefix sum
    offs[t] = excl;
    curs[t] = excl;
    if (t == NGRP - 1) offs[NGRP] = NCLS;
}

__global__ __launch_bounds__(512) void k_scatter(const int* __restrict__ sid,
                                                 int* __restrict__ curs,
                                                 unsigned short* __restrict__ cols16) {
    int c = blockIdx.x * 512 + threadIdx.x;
    int g = sid[c];
    int pos = atomicAdd(&curs[g], 1);  // order within group irrelevant (sum)
    cols16[pos] = (unsigned short)c;
}

// Stage a ROW PAIR into pair-interleaved LDS. Wave w covers chunks
// j = w*16..w*16+15; per instr: lanes 0-31 bring 512B of row r0 chunk j,
// lanes 32-63 bring 512B of row r1 chunk j; dest = chunk base (wave-uniform)
// + lane*16 -> [r0 512B | r1 512B] exactly.
#define STAGE_PAIR(dstbuf, r0idx)                                                 \
    do {                                                                          \
        const float* xp_ = x + (size_t)((r0idx) + (lane >> 5)) * NCLS +           \
                           (lane & 31) * 4;                                       \
        _Pragma("unroll")                                                         \
        for (int k_ = 0; k_ < 16; ++k_) {                                         \
            const int j_ = wid * 16 + k_;                                         \
            __builtin_amdgcn_global_load_lds(                                     \
                (const __attribute__((address_space(1))) void*)(xp_ + j_ * 128),  \
                (__attribute__((address_space(3))) void*)(&dstbuf[j_ * 256]),     \
                16, 0, 0);                                                        \
        }                                                                         \
    } while (0)

// Gather this thread's 2 segments for BOTH planes; one u64 col read = 4 ids;
// each id -> ds_read pair (idx, idx+128). Branch-free edges via weight-FMA.
#define GATHER_STORE(srcbuf, r0idx)                                               \
    do {                                                                          \
        float s00_, s01_, s10_, s11_;                                             \
        _Pragma("unroll")                                                         \
        for (int j_ = 0; j_ < 2; ++j_) {                                          \
            const int s_ = (j_ == 0) ? o0 : o1;                                   \
            const int e_ = (j_ == 0) ? o1 : o2;                                   \
            float pa0 = 0.f, pa1 = 0.f, pa2 = 0.f, pa3 = 0.f;                     \
            float pb0 = 0.f, pb1 = 0.f, pb2 = 0.f, pb3 = 0.f;                     \
            for (int p_ = (s_ & ~3); p_ < e_; p_ += 4) {                          \
                unsigned long long cc_ =                                          \
                    *reinterpret_cast<const unsigned long long*>(&colb[p_]);      \
                const int c0_ = (int)(cc_ & 0xffffu);                             \
                const int c1_ = (int)((cc_ >> 16) & 0xffffu);                     \
                const int c2_ = (int)((cc_ >> 32) & 0xffffu);                     \
                const int c3_ = (int)(cc_ >> 48);                                 \
                const int i0_ = c0_ + (c0_ & ~127);                               \
                const int i1_ = c1_ + (c1_ & ~127);                               \
                const int i2_ = c2_ + (c2_ & ~127);                               \
                const int i3_ = c3_ + (c3_ & ~127);                               \
                const float w0_ = (p_ >= s_) ? 1.f : 0.f;                         \
                const float w1_ = (p_ + 1 >= s_ && p_ + 1 < e_) ? 1.f : 0.f;      \
                const float w2_ = (p_ + 2 >= s_ && p_ + 2 < e_) ? 1.f : 0.f;      \
                const float w3_ = (p_ + 3 < e_) ? 1.f : 0.f;                      \
                pa0 = fmaf(w0_, srcbuf[i0_], pa0);                                \
                pb0 = fmaf(w0_, srcbuf[i0_ + 128], pb0);                          \
                pa1 = fmaf(w1_, srcbuf[i1_], pa1);                                \
                pb1 = fmaf(w1_, srcbuf[i1_ + 128], pb1);                          \
                pa2 = fmaf(w2_, srcbuf[i2_], pa2);                                \
                pb2 = fmaf(w2_, srcbuf[i2_ + 128], pb2);                          \
                pa3 = fmaf(w3_, srcbuf[i3_], pa3);                                \
                pb3 = fmaf(w3_, srcbuf[i3_ + 128], pb3);                          \
            }                                                                     \
            const float sa_ = (pa0 + pa1) + (pa2 + pa3);                          \
            const float sb_ = (pb0 + pb1) + (pb2 + pb3);                          \
            if (j_ == 0) { s00_ = sa_; s10_ = sb_; }                              \
            else         { s01_ = sa_; s11_ = sb_; }                              \
        }                                                                         \
        vf2 v0_, v1_;                                                             \
        v0_.x = s00_; v0_.y = s01_;                                               \
        v1_.x = s10_; v1_.y = s11_;                                               \
        float* op_ = out + (size_t)(r0idx)*NGRP + g0;                             \
        __builtin_nontemporal_store(v0_, reinterpret_cast<vf2*>(op_));            \
        __builtin_nontemporal_store(v1_, reinterpret_cast<vf2*>(op_ + NGRP));     \
    } while (0)

#define WAIT_VM(n) asm volatile("s_waitcnt vmcnt(" #n ")" ::: "memory")

__global__ __launch_bounds__(TPB) void k_main(const float* __restrict__ x,
                                              const unsigned short* __restrict__ cols16,
                                              const int* __restrict__ offs,
                                              float* __restrict__ out) {
    __shared__ unsigned short colb[NCLS];  // 16 KB
    __shared__ float pairA[NCLS * 2];      // 64 KB: [j][plane][128] blocked pairs
    __shared__ float pairB[NCLS * 2];      // 64 KB: double buffer -> 144 KB total
    const int tid  = threadIdx.x;          // 0..255, 4 waves
    const int wid  = tid >> 6;
    const int lane = tid & 63;
    const int g0   = tid * 2;              // this thread's 2 groups
    const int row0 = blockIdx.x * RPB;

    // --- prologue: colb DMA + stage pair 0 ---
    // One DMA instr = 64 lanes x 16B = 512 u16. 16 instrs (4/wave) at 512-u16
    // spacing cover all 8192 ids. (R9 bug: was spaced 1024 -> half garbage.)
#pragma unroll
    for (int k = 0; k < 4; ++k) {
        const int j2 = wid * 4 + k;
        __builtin_amdgcn_global_load_lds(
            (const __attribute__((address_space(1))) void*)(cols16 + j2 * 512 + lane * 8),
            (__attribute__((address_space(3))) void*)(&colb[j2 * 512]),
            16, 0, 0);
    }
    STAGE_PAIR(pairA, row0);

    // Segment boundaries (row-invariant).
    int o0, o1, o2;
    {
        int2 q = *reinterpret_cast<const int2*>(offs + g0);
        o0 = q.x;
        o1 = q.y;
        o2 = offs[g0 + 2];
    }
    WAIT_VM(0);
    __syncthreads();

    // --- main loop: 16 pair phases, x2 unrolled for distinct buffers ---
#pragma unroll 1
    for (int ph = 0; ph < NPH; ph += 2) {
        const int rA = row0 + 2 * ph;

        // A phase: pairA ready for all waves.
        if (ph + 1 < NPH) STAGE_PAIR(pairB, rA + 2);
        GATHER_STORE(pairA, rA);
        WAIT_VM(2);          // drain my 16 stage DMAs; leave my 2 output stores
        __syncthreads();

        // B phase: pairB ready.
        if (ph + 2 < NPH) STAGE_PAIR(pairA, rA + 4);
        GATHER_STORE(pairB, rA + 2);
        WAIT_VM(2);
        __syncthreads();
    }
}

extern "C" void kernel_launch(void* const* d_in, const int* in_sizes, int n_in,
                              void* d_out, int out_size, void* d_ws, size_t ws_size,
                              hipStream_t stream) {
    const float* x   = (const float*)d_in[0];
    const int*   sid = (const int*)d_in[1];
    float*       out = (float*)d_out;

    int* ws   = (int*)d_ws;
    int* hist = ws;
    int* offs = ws + 512;
    int* curs = ws + 1088;
    unsigned short* cols16 = (unsigned short*)(ws + 1600);

    const int batch  = in_sizes[0] / NCLS;   // 8192
    const int blocks = batch / RPB;          // 256

    hipMemsetAsync(hist, 0, NGRP * sizeof(int), stream);
    k_hist<<<NCLS / 512, 512, 0, stream>>>(sid, hist);
    k_scan<<<1, NGRP, 0, stream>>>(hist, offs, curs);
    k_scatter<<<NCLS / 512, 512, 0, stream>>>(sid, curs, cols16);
    k_main<<<blocks, TPB, 0, stream>>>(x, cols16, offs, out);
}

// Round 8
// 364.684 us; speedup vs baseline: 1.2303x; 1.0095x over previous
//
#include <hip/hip_runtime.h>

// Aggregate = column segment-sum: out[b][g] = sum_{c: sid[c]==g} x[b][c]
// x: [8192, 8192] f32, sid: [8192] i32 in [0,512), out: [8192, 512] f32.
//
// R1 341us atomics; R2/R3 ~170 barrier-phased; R4 224 global cols;
// R5/R6 178-180; R7/R8 totals 415/379.5; R9 pair-interleave (bugs) failed;
// R10 pair-interleave fixed: 368.1 total (-11 vs R8) — op-count cuts barely
// move it. All pipes <15% busy in every structure: the wall is exposed
// latency. R10 ran 1 wave/SIMD (4 waves/CU): NOTHING co-resident to issue
// during col->gather dependent hops and DMA drains.
// R11 (this): R10 layout bit-identical, TPB 256->512 = 8 waves, 2/SIMD,
//     still 1 block/CU (144KB LDS). Thread owns 1 group (shorter chains);
//     per-wave DMA 8 instrs/phase; each SIMD has a partner wave to hide
//     ds_read/vmcnt stalls. Isolates per-SIMD occupancy vs R10.
//   - pair[j][plane][128]: col c of (r0,r1) at idx=c+(c&~127), idx+128;
//     split-lane DMA (lanes 0-31 row r0, 32-63 row r1), LDS dest linear.
//   - Counted waits: stage next pair -> gather current -> vmcnt(2) -> barrier.
//   - Prep chain BIT-IDENTICAL to R7/R8/R10.

#define NCLS 8192
#define NGRP 512
#define TPB  512
#define RPB  32    // rows per block -> 256 blocks, 1/CU
#define NPH  16    // pair phases per block

typedef float vf2 __attribute__((ext_vector_type(2)));

// d_ws (ints): hist[512] @0, offs[513] @512, curs[512] @1088, cols16 u16[8192] @1600

__global__ __launch_bounds__(512) void k_hist(const int* __restrict__ sid,
                                              int* __restrict__ hist) {
    int i = blockIdx.x * 512 + threadIdx.x;
    atomicAdd(&hist[sid[i]], 1);
}

__global__ __launch_bounds__(512) void k_scan(const int* __restrict__ hist,
                                              int* __restrict__ offs,
                                              int* __restrict__ curs) {
    __shared__ int tmp[NGRP];
    const int t = threadIdx.x;
    const int h = hist[t];
    tmp[t] = h;
    __syncthreads();
    for (int off = 1; off < NGRP; off <<= 1) {
        int v = tmp[t];
        int u = (t >= off) ? tmp[t - off] : 0;
        __syncthreads();
        tmp[t] = v + u;
        __syncthreads();
    }
    int excl = tmp[t] - h;   // exclusive prefix sum
    offs[t] = excl;
    curs[t] = excl;
    if (t == NGRP - 1) offs[NGRP] = NCLS;
}

__global__ __launch_bounds__(512) void k_scatter(const int* __restrict__ sid,
                                                 int* __restrict__ curs,
                                                 unsigned short* __restrict__ cols16) {
    int c = blockIdx.x * 512 + threadIdx.x;
    int g = sid[c];
    int pos = atomicAdd(&curs[g], 1);  // order within group irrelevant (sum)
    cols16[pos] = (unsigned short)c;
}

// Stage a ROW PAIR into pair-interleaved LDS. 8 waves x 8 chunks = 64 chunks
// of 1KB ([r0 512B | r1 512B]); per instr lanes 0-31 bring 512B of row r0,
// lanes 32-63 of row r1; dest = chunk base (wave-uniform) + lane*16.
#define STAGE_PAIR(dstbuf, r0idx)                                                 \
    do {                                                                          \
        const float* xp_ = x + (size_t)((r0idx) + (lane >> 5)) * NCLS +           \
                           (lane & 31) * 4;                                       \
        _Pragma("unroll")                                                         \
        for (int k_ = 0; k_ < 8; ++k_) {                                          \
            const int j_ = wid * 8 + k_;                                          \
            __builtin_amdgcn_global_load_lds(                                     \
                (const __attribute__((address_space(1))) void*)(xp_ + j_ * 128),  \
                (__attribute__((address_space(3))) void*)(&dstbuf[j_ * 256]),     \
                16, 0, 0);                                                        \
        }                                                                         \
    } while (0)

// Gather this thread's ONE segment for both planes; one u64 col read = 4 ids;
// each id -> ds_read pair (idx, idx+128). Branch-free edges via weight-FMA.
// Two scalar f32 stores (coalesced across threads: g0 = tid).
#define GATHER_STORE(srcbuf, r0idx)                                               \
    do {                                                                          \
        float pa0 = 0.f, pa1 = 0.f, pa2 = 0.f, pa3 = 0.f;                         \
        float pb0 = 0.f, pb1 = 0.f, pb2 = 0.f, pb3 = 0.f;                         \
        for (int p_ = (o0 & ~3); p_ < o1; p_ += 4) {                              \
            unsigned long long cc_ =                                              \
                *reinterpret_cast<const unsigned long long*>(&colb[p_]);          \
            const int c0_ = (int)(cc_ & 0xffffu);                                 \
            const int c1_ = (int)((cc_ >> 16) & 0xffffu);                         \
            const int c2_ = (int)((cc_ >> 32) & 0xffffu);                         \
            const int c3_ = (int)(cc_ >> 48);                                     \
            const int i0_ = c0_ + (c0_ & ~127);                                   \
            const int i1_ = c1_ + (c1_ & ~127);                                   \
            const int i2_ = c2_ + (c2_ & ~127);                                   \
            const int i3_ = c3_ + (c3_ & ~127);                                   \
            const float w0_ = (p_ >= o0) ? 1.f : 0.f;                             \
            const float w1_ = (p_ + 1 >= o0 && p_ + 1 < o1) ? 1.f : 0.f;          \
            const float w2_ = (p_ + 2 >= o0 && p_ + 2 < o1) ? 1.f : 0.f;          \
            const float w3_ = (p_ + 3 < o1) ? 1.f : 0.f;                          \
            pa0 = fmaf(w0_, srcbuf[i0_], pa0);                                    \
            pb0 = fmaf(w0_, srcbuf[i0_ + 128], pb0);                              \
            pa1 = fmaf(w1_, srcbuf[i1_], pa1);                                    \
            pb1 = fmaf(w1_, srcbuf[i1_ + 128], pb1);                              \
            pa2 = fmaf(w2_, srcbuf[i2_], pa2);                                    \
            pb2 = fmaf(w2_, srcbuf[i2_ + 128], pb2);                              \
            pa3 = fmaf(w3_, srcbuf[i3_], pa3);                                    \
            pb3 = fmaf(w3_, srcbuf[i3_ + 128], pb3);                              \
        }                                                                         \
        const float sa_ = (pa0 + pa1) + (pa2 + pa3);                              \
        const float sb_ = (pb0 + pb1) + (pb2 + pb3);                              \
        float* op_ = out + (size_t)(r0idx)*NGRP + g0;                             \
        __builtin_nontemporal_store(sa_, op_);                                    \
        __builtin_nontemporal_store(sb_, op_ + NGRP);                             \
    } while (0)

#define WAIT_VM(n) asm volatile("s_waitcnt vmcnt(" #n ")" ::: "memory")

__global__ __launch_bounds__(TPB) void k_main(const float* __restrict__ x,
                                              const unsigned short* __restrict__ cols16,
                                              const int* __restrict__ offs,
                                              float* __restrict__ out) {
    __shared__ unsigned short colb[NCLS];  // 16 KB
    __shared__ float pairA[NCLS * 2];      // 64 KB: [j][plane][128] blocked pairs
    __shared__ float pairB[NCLS * 2];      // 64 KB: double buffer -> 144 KB total
    const int tid  = threadIdx.x;          // 0..511, 8 waves (2/SIMD)
    const int wid  = tid >> 6;
    const int lane = tid & 63;
    const int g0   = tid;                  // this thread's ONE group
    const int row0 = blockIdx.x * RPB;

    // --- prologue: colb DMA + stage pair 0 ---
    // One DMA instr = 512 u16; 16 instrs (2/wave) at 512-u16 spacing.
#pragma unroll
    for (int k = 0; k < 2; ++k) {
        const int j2 = wid * 2 + k;
        __builtin_amdgcn_global_load_lds(
            (const __attribute__((address_space(1))) void*)(cols16 + j2 * 512 + lane * 8),
            (__attribute__((address_space(3))) void*)(&colb[j2 * 512]),
            16, 0, 0);
    }
    STAGE_PAIR(pairA, row0);

    // Segment boundaries (row-invariant): one group per thread.
    const int o0 = offs[g0];
    const int o1 = offs[g0 + 1];

    WAIT_VM(0);
    __syncthreads();

    // --- main loop: 16 pair phases, x2 unrolled for distinct buffers ---
#pragma unroll 1
    for (int ph = 0; ph < NPH; ph += 2) {
        const int rA = row0 + 2 * ph;

        // A phase: pairA ready for all waves.
        if (ph + 1 < NPH) STAGE_PAIR(pairB, rA + 2);
        GATHER_STORE(pairA, rA);
        WAIT_VM(2);          // drain my 8 stage DMAs; leave my 2 output stores
        __syncthreads();

        // B phase: pairB ready.
        if (ph + 2 < NPH) STAGE_PAIR(pairA, rA + 4);
        GATHER_STORE(pairB, rA + 2);
        WAIT_VM(2);
        __syncthreads();
    }
}

extern "C" void kernel_launch(void* const* d_in, const int* in_sizes, int n_in,
                              void* d_out, int out_size, void* d_ws, size_t ws_size,
                              hipStream_t stream) {
    const float* x   = (const float*)d_in[0];
    const int*   sid = (const int*)d_in[1];
    float*       out = (float*)d_out;

    int* ws   = (int*)d_ws;
    int* hist = ws;
    int* offs = ws + 512;
    int* curs = ws + 1088;
    unsigned short* cols16 = (unsigned short*)(ws + 1600);

    const int batch  = in_sizes[0] / NCLS;   // 8192
    const int blocks = batch / RPB;          // 256

    hipMemsetAsync(hist, 0, NGRP * sizeof(int), stream);
    k_hist<<<NCLS / 512, 512, 0, stream>>>(sid, hist);
    k_scan<<<1, NGRP, 0, stream>>>(hist, offs, curs);
    k_scatter<<<NCLS / 512, 512, 0, stream>>>(sid, curs, cols16);
    k_main<<<blocks, TPB, 0, stream>>>(x, cols16, offs, out);
}